// Round 3
// baseline (127.593 us; speedup 1.0000x reference)
//
#include <hip/hip_runtime.h>
#include <math.h>

#define B 128
#define N 1024
#define C 384
#define C4 96                   // C/4
#define XROWS 1025
#define OUTROWS 257

typedef float f32x4 __attribute__((ext_vector_type(4)));

// workspace layout (float offsets)
#define OFF_FLAGS 0                        // 512 ints: flagEA[B], flagX[B], done
#define OFF_EAP   512                      // [B][2][C] ea half column-sums
#define SZ_EAP    (B * 2 * C)
#define OFF_NAPH  (OFF_EAP + SZ_EAP)       // [B][C] na partial from g==1
#define SZ_NAPH   (B * C)
#define OFF_NA    (OFF_NAPH + SZ_NAPH)     // [B][C]
#define SZ_NA     (B * C)
#define OFF_SQ    (OFF_NA + SZ_NA)         // [0,B): sumsq(na), [B,2B): sumsq(cls)
#define SZ_SQ     (2 * B)
#define OFF_DOTS  (OFF_SQ + SZ_SQ)         // [B][N]
#define SZ_DOTS   (B * N)

__device__ __forceinline__ float sigmoidf(float v) { return 1.f / (1.f + expf(-v)); }
__device__ __forceinline__ float dot4v(f32x4 a, f32x4 b) {
    return a.x * b.x + a.y * b.y + a.z * b.z + a.w * b.w;
}
__device__ __forceinline__ void st_ag(float* p, float v) {
    __hip_atomic_store(p, v, __ATOMIC_RELAXED, __HIP_MEMORY_SCOPE_AGENT);
}
__device__ __forceinline__ float ld_ag(const float* p) {
    return __hip_atomic_load(p, __ATOMIC_RELAXED, __HIP_MEMORY_SCOPE_AGENT);
}

// fat2: grid (B,2) x 1024.  block (b,g) owns rows [g*512,(g+1)*512) of batch b.
// Pair handshakes (device-scope flags) replace kernel boundaries:
//   P0 ea half-sum -> flagEA -> ci | P1 x half-pass -> flagX -> sort(redundant) + gather half.
// g==0 additionally finishes na/sumsq; the LAST g==0 block writes all cls rows.
__global__ __launch_bounds__(1024) void fat2(const float* __restrict__ x,
                                             const float* __restrict__ cls,
                                             const float* __restrict__ ea,
                                             int* __restrict__ flags,
                                             float* __restrict__ eaP,
                                             float* __restrict__ naPh,
                                             float* __restrict__ na,
                                             float* __restrict__ sqp,
                                             float* __restrict__ dotsG,
                                             float* __restrict__ out) {
    int b = blockIdx.x, g = blockIdx.y, tid = threadIdx.x;
    int w = tid >> 6, lane = tid & 63, hl = lane & 31, half = lane >> 5;

    __shared__ float sci[C];                // 1.5 KB
    __shared__ float dotsL[512];            // 2 KB (own-half dots; epilogue scratch)
    __shared__ f32x4 sacc[16][C4];          // 24 KB
    __shared__ unsigned long long bufA[N];  // 8 KB
    __shared__ unsigned long long bufB[N];  // 8 KB
    __shared__ unsigned llist[256];         // 1 KB
    __shared__ float escr[2 * C4];          // 768 B
    __shared__ int lastB;
    if (tid == 0) lastB = 0;

    int* flagEA = flags;
    int* flagX  = flags + B;
    int* done   = flags + 2 * B;

    // ---------- P0: ea half column-sum (512 rows, nontemporal) ----------
    {
        const float* eb = ea + ((size_t)b * N + (size_t)g * 512) * C;
        f32x4 eacc[3];
#pragma unroll
        for (int k = 0; k < 3; ++k) eacc[k] = (f32x4)(0.f);
#pragma unroll 2
        for (int it = 0; it < 16; ++it) {
            int r = 32 * it + 2 * w + half;
            const f32x4* rp = (const f32x4*)(eb + (size_t)r * C);
#pragma unroll
            for (int k = 0; k < 3; ++k)
                eacc[k] += __builtin_nontemporal_load(&rp[hl + 32 * k]);
        }
#pragma unroll
        for (int k = 0; k < 3; ++k) {
            eacc[k].x += __shfl_xor(eacc[k].x, 32, 64);
            eacc[k].y += __shfl_xor(eacc[k].y, 32, 64);
            eacc[k].z += __shfl_xor(eacc[k].z, 32, 64);
            eacc[k].w += __shfl_xor(eacc[k].w, 32, 64);
        }
        if (half == 0) {
#pragma unroll
            for (int k = 0; k < 3; ++k) sacc[w][hl + 32 * k] = eacc[k];
        }
    }
    __syncthreads();
    f32x4 s0 = (f32x4)(0.f);
    if (tid < C4) {
#pragma unroll
        for (int w2 = 0; w2 < 16; ++w2) s0 += sacc[w2][tid];
        float* pe = &eaP[((size_t)b * 2 + g) * C + 4 * tid];
        st_ag(pe + 0, s0.x); st_ag(pe + 1, s0.y);
        st_ag(pe + 2, s0.z); st_ag(pe + 3, s0.w);
    }
    __syncthreads();   // drain eaP stores (vmcnt) before signal
    if (tid == 0) {
        __threadfence();
        __hip_atomic_fetch_add(flagEA + b, 1, __ATOMIC_RELEASE, __HIP_MEMORY_SCOPE_AGENT);
        while (__hip_atomic_load(flagEA + b, __ATOMIC_ACQUIRE, __HIP_MEMORY_SCOPE_AGENT) < 2)
            __builtin_amdgcn_s_sleep(1);
    }
    __syncthreads();
    if (tid < C4) {
        const float* pe = &eaP[((size_t)b * 2 + (1 - g)) * C + 4 * tid];
        f32x4 sp;
        sp.x = ld_ag(pe + 0); sp.y = ld_ag(pe + 1);
        sp.z = ld_ag(pe + 2); sp.w = ld_ag(pe + 3);
        f32x4 m = (s0 + sp) * (1.f / (float)N);
        sci[4 * tid + 0] = sigmoidf(m.x);
        sci[4 * tid + 1] = sigmoidf(m.y);
        sci[4 * tid + 2] = sigmoidf(m.z);
        sci[4 * tid + 3] = sigmoidf(m.w);
    }
    __syncthreads();

    // ---------- P1: x-pass over own half ----------
    f32x4 cir[3];
#pragma unroll
    for (int k = 0; k < 3; ++k) cir[k] = ((const f32x4*)sci)[hl + 32 * k];
    f32x4 acc[3];
#pragma unroll
    for (int k = 0; k < 3; ++k) acc[k] = (f32x4)(0.f);

    const float* xb = x + (size_t)b * XROWS * C + C + (size_t)g * 512 * C;
#pragma unroll 2
    for (int it = 0; it < 16; ++it) {
        int r = 32 * it + 2 * w + half;
        const f32x4* rp = (const f32x4*)(xb + (size_t)r * C);
        f32x4 v[3];
        float dotv = 0.f;
#pragma unroll
        for (int k = 0; k < 3; ++k) {
            v[k] = rp[hl + 32 * k];
            dotv += dot4v(v[k], cir[k]);
        }
#pragma unroll
        for (int off = 16; off > 0; off >>= 1) dotv += __shfl_xor(dotv, off, 64);
        if (hl == 0) {
            dotsL[r] = dotv;
            st_ag(&dotsG[(size_t)b * N + g * 512 + r], dotv);
        }
        float si = sigmoidf(dotv);
#pragma unroll
        for (int k = 0; k < 3; ++k) acc[k] += si * v[k];
    }
#pragma unroll
    for (int k = 0; k < 3; ++k) {
        acc[k].x += __shfl_xor(acc[k].x, 32, 64);
        acc[k].y += __shfl_xor(acc[k].y, 32, 64);
        acc[k].z += __shfl_xor(acc[k].z, 32, 64);
        acc[k].w += __shfl_xor(acc[k].w, 32, 64);
    }
    if (half == 0) {
#pragma unroll
        for (int k = 0; k < 3; ++k) sacc[w][hl + 32 * k] = acc[k];
    }
    __syncthreads();
    f32x4 sNA = (f32x4)(0.f);
    if (tid < C4) {
#pragma unroll
        for (int w2 = 0; w2 < 16; ++w2) sNA += sacc[w2][tid];
        if (g == 1) {
            float* pn = &naPh[(size_t)b * C + 4 * tid];
            st_ag(pn + 0, sNA.x); st_ag(pn + 1, sNA.y);
            st_ag(pn + 2, sNA.z); st_ag(pn + 3, sNA.w);
        }
    }
    __syncthreads();   // drain dotsG/naPh stores before signal
    if (tid == 0) {
        __threadfence();
        __hip_atomic_fetch_add(flagX + b, 1, __ATOMIC_RELEASE, __HIP_MEMORY_SCOPE_AGENT);
        while (__hip_atomic_load(flagX + b, __ATOMIC_ACQUIRE, __HIP_MEMORY_SCOPE_AGENT) < 2)
            __builtin_amdgcn_s_sleep(1);
    }
    __syncthreads();

    // ---------- g==0: finish na, per-batch sumsq, done-count ----------
    if (g == 0) {
        if (tid < C4) {
            const float* pn = &naPh[(size_t)b * C + 4 * tid];
            sNA.x += ld_ag(pn + 0); sNA.y += ld_ag(pn + 1);
            sNA.z += ld_ag(pn + 2); sNA.w += ld_ag(pn + 3);
            float* po = &na[(size_t)b * C + 4 * tid];
            st_ag(po + 0, sNA.x); st_ag(po + 1, sNA.y);
            st_ag(po + 2, sNA.z); st_ag(po + 3, sNA.w);
            escr[tid] = dot4v(sNA, sNA);
            f32x4 cv = ((const f32x4*)(cls + (size_t)b * C))[tid];
            escr[C4 + tid] = dot4v(cv, cv);
        }
        __syncthreads();
        if (w == 0) {
            float nss = (lane < 32) ? (escr[lane] + escr[lane + 32] + escr[lane + 64]) : 0.f;
            float css = (lane < 32) ? (escr[C4 + lane] + escr[C4 + lane + 32] + escr[C4 + lane + 64]) : 0.f;
#pragma unroll
            for (int off = 32; off > 0; off >>= 1) {
                nss += __shfl_xor(nss, off, 64);
                css += __shfl_xor(css, off, 64);
            }
            if (lane == 0) { st_ag(&sqp[b], nss); st_ag(&sqp[B + b], css); }
        }
        __syncthreads();
        if (tid == 0) {
            __threadfence();
            int old = __hip_atomic_fetch_add(done, 1, __ATOMIC_ACQ_REL, __HIP_MEMORY_SCOPE_AGENT);
            if (old == B - 1) lastB = 1;
        }
    }

    // ---------- sort: full 1024 dots (own half LDS, partner half agent-load) ----------
    float vv = ((tid >> 9) == g) ? dotsL[tid & 511] : ld_ag(&dotsG[(size_t)b * N + tid]);
    unsigned u = __float_as_uint(vv);
    u = (u & 0x80000000u) ? ~u : (u | 0x80000000u);
    unsigned long long key = ((unsigned long long)u << 32) | (unsigned)tid;

    bool useA = true;
    for (int k = 2; k <= N; k <<= 1) {
        bool up = ((tid & k) == 0);
        for (int j = k >> 1; j > 0; j >>= 1) {
            unsigned long long other;
            if (j < 64) {
                other = __shfl_xor(key, j, 64);
            } else {
                unsigned long long* buf = useA ? bufA : bufB;
                useA = !useA;
                buf[tid] = key;
                __syncthreads();
                other = buf[tid ^ j];
            }
            bool iAmLow = ((tid & j) == 0);
            bool keepMin = (iAmLow == up);
            bool otherLess = (other < key);
            key = (keepMin == otherLess) ? other : key;
        }
    }
    __syncthreads();   // drain last LDS-stage reads

    // ---------- node-ascending (node, outpos) list ----------
    unsigned* flag = (unsigned*)bufA;
    unsigned* wsum = (unsigned*)bufB;
    flag[tid] = 0;
    __syncthreads();
    if (tid >= 768) flag[(unsigned)(key & 1023u)] = (unsigned)(tid - 768) | 0x80000000u;
    __syncthreads();
    unsigned f = flag[tid];
    bool sel = (f & 0x80000000u) != 0;
    unsigned long long bal = __ballot(sel);
    if (lane == 0) wsum[w] = (unsigned)__popcll(bal);
    __syncthreads();
    if (sel) {
        int base = 0;
        for (int w2 = 0; w2 < w; ++w2) base += (int)wsum[w2];
        int intra = (int)__popcll(bal & ((1ull << lane) - 1ull));
        llist[base + intra] = ((unsigned)tid << 8) | (f & 0xFFu);
    }
    __syncthreads();

    // ---------- gather own 128 pooled rows (x L2/L3-warm, pair on same XCD) ----------
    const float* xb2 = x + ((size_t)b * XROWS + 1) * C;
#pragma unroll 4
    for (int q = 0; q < 12; ++q) {
        int e = tid + 1024 * q;
        int lp = 128 * g + e / C4, c4 = e % C4;
        unsigned ent = llist[lp];
        int node = (int)(ent >> 8);
        int op = (int)(ent & 0xFFu);
        f32x4 sv = *((const f32x4*)(xb2 + (size_t)node * C) + c4);
        __builtin_nontemporal_store(sv,
            (f32x4*)(out + ((size_t)b * OUTROWS + 1 + op) * C) + c4);
    }

    // ---------- last-block epilogue: global norms + all cls rows ----------
    __syncthreads();
    if (lastB) {
        if (tid < 128) {
            dotsL[tid]       = ld_ag(&sqp[tid]);
            dotsL[256 + tid] = ld_ag(&sqp[B + tid]);
        }
        __syncthreads();
        if (tid == 0) {
            float nss = 0.f, css = 0.f;
            for (int i = 0; i < 128; ++i) { nss += dotsL[i]; css += dotsL[256 + i]; }
            escr[0] = sqrtf(css / nss);   // ||cls|| / ||na||
        }
        __syncthreads();
        float ratio = escr[0];
        for (int e = tid; e < B * C; e += 1024) {
            int bb = e / C, c = e - bb * C;
            out[(size_t)bb * OUTROWS * C + c] = cls[e] + ratio * ld_ag(&na[e]);
        }
    }
}

extern "C" void kernel_launch(void* const* d_in, const int* in_sizes, int n_in,
                              void* d_out, int out_size, void* d_ws, size_t ws_size,
                              hipStream_t stream) {
    const float* x   = (const float*)d_in[0];
    const float* cls = (const float*)d_in[1];
    const float* ea  = (const float*)d_in[2];
    float* out = (float*)d_out;
    float* ws  = (float*)d_ws;

    int*   flags = (int*)ws;
    float* eaP   = ws + OFF_EAP;
    float* naPh  = ws + OFF_NAPH;
    float* na    = ws + OFF_NA;
    float* sqp   = ws + OFF_SQ;
    float* dotsG = ws + OFF_DOTS;

    hipMemsetAsync(flags, 0, 2048, stream);   // zero flagEA/flagX/done (poison-proof)
    fat2<<<dim3(B, 2), 1024, 0, stream>>>(x, cls, ea, flags, eaP, naPh, na, sqp, dotsG, out);
}

// Round 4
// 91.862 us; speedup vs baseline: 1.3890x; 1.3890x over previous
//
#include <hip/hip_runtime.h>
#include <math.h>

#define B 128
#define N 1024
#define C 384
#define C4 96                   // C/4
#define NS 8                    // splits for ea partial pass
#define RPT (N / NS)            // 128
#define XROWS 1025
#define OUTROWS 257

typedef float f32x4 __attribute__((ext_vector_type(4)));

// workspace layout (float offsets)
#define OFF_EAP  0                       // [B][NS][C]
#define SZ_EAP   (B * NS * C)
#define OFF_NA   (OFF_EAP + SZ_EAP)      // [B][C]
#define SZ_NA    (B * C)
#define OFF_SQ   (OFF_NA + SZ_NA)        // [0,B): sumsq(na), [B,2B): sumsq(cls)
#define SZ_SQ    (2 * B)

__device__ __forceinline__ float sigmoidf(float v) { return 1.f / (1.f + expf(-v)); }
__device__ __forceinline__ float dot4v(f32x4 a, f32x4 b) {
    return a.x * b.x + a.y * b.y + a.z * b.z + a.w * b.w;
}

// ---------------- k1: partial column sums of edge_aggregation (f32x4, nontemporal) --------------
__global__ __launch_bounds__(384) void k1_ea_partial(const float* __restrict__ ea,
                                                     float* __restrict__ eaP) {
    int b = blockIdx.x, s = blockIdx.y, t = threadIdx.x;
    int rg = t / C4, c4 = t % C4;
    const f32x4* p = (const f32x4*)(ea + ((size_t)b * N + (size_t)s * RPT) * C);
    f32x4 acc = (f32x4)(0.f);
#pragma unroll 8
    for (int it = 0; it < RPT / 4; ++it)
        acc += __builtin_nontemporal_load(&p[(size_t)(it * 4 + rg) * C4 + c4]);
    __shared__ f32x4 lds[4][C4];
    lds[rg][c4] = acc;
    __syncthreads();
    if (t < C4) {
        f32x4 r = lds[0][t] + lds[1][t] + lds[2][t] + lds[3][t];
        ((f32x4*)(eaP + ((size_t)b * NS + s) * C))[t] = r;
    }
}

// ---------------- fatk: 1 block/batch: ci -> x-pass (2 rows/half-wave) -> sort -> gather -------
__global__ __launch_bounds__(1024) void fatk(const float* __restrict__ x,
                                             const float* __restrict__ cls,
                                             const float* __restrict__ eaP,
                                             float* __restrict__ na,
                                             float* __restrict__ sqp,
                                             float* __restrict__ out) {
    int b = blockIdx.x, tid = threadIdx.x;
    int w = tid >> 6, lane = tid & 63, hl = lane & 31, half = lane >> 5;

    __shared__ f32x4 eap[NS][C4];           // 12 KB (later float scratch)
    __shared__ float sci[C];                // 1.5 KB
    __shared__ float dots[N];               // 4 KB
    __shared__ f32x4 sacc[16][C4];          // 24 KB
    __shared__ unsigned long long bufA[N];  // 8 KB
    __shared__ unsigned long long bufB[N];  // 8 KB
    __shared__ unsigned llist[256];         // 1 KB
    __shared__ unsigned wsumS[16];

    // ---------- ci = sigmoid(mean) from the NS eaP partials (12 KB, L2-hot) ----------
    if (tid < NS * C4) {
        int rg = tid / C4, c4 = tid % C4;
        eap[rg][c4] = ((const f32x4*)(eaP + ((size_t)b * NS + rg) * C))[c4];
    }
    __syncthreads();
    if (tid < C4) {
        f32x4 s = (f32x4)(0.f);
#pragma unroll
        for (int r = 0; r < NS; ++r) s += eap[r][tid];
        s *= (1.f / (float)N);
        sci[4 * tid + 0] = sigmoidf(s.x);
        sci[4 * tid + 1] = sigmoidf(s.y);
        sci[4 * tid + 2] = sigmoidf(s.z);
        sci[4 * tid + 3] = sigmoidf(s.w);
    }
    __syncthreads();

    // ---------- x-pass: 2 rows per half-wave per iter (12 indep loads/wave in flight) ----------
    f32x4 cir[3];
#pragma unroll
    for (int k = 0; k < 3; ++k) cir[k] = ((const f32x4*)sci)[hl + 32 * k];
    f32x4 acc[3];
#pragma unroll
    for (int k = 0; k < 3; ++k) acc[k] = (f32x4)(0.f);

    const float* xb = x + (size_t)b * XROWS * C + C;   // nodes base (skip cls row)
#pragma unroll 2
    for (int it = 0; it < 16; ++it) {
        int r0 = 64 * it + 4 * w + 2 * half;           // this half-wave's row pair
        const f32x4* rp0 = (const f32x4*)(xb + (size_t)r0 * C);
        const f32x4* rp1 = (const f32x4*)(xb + (size_t)(r0 + 1) * C);
        f32x4 v0[3], v1[3];
#pragma unroll
        for (int k = 0; k < 3; ++k) v0[k] = rp0[hl + 32 * k];
#pragma unroll
        for (int k = 0; k < 3; ++k) v1[k] = rp1[hl + 32 * k];
        float d0 = 0.f, d1 = 0.f;
#pragma unroll
        for (int k = 0; k < 3; ++k) {
            d0 += dot4v(v0[k], cir[k]);
            d1 += dot4v(v1[k], cir[k]);
        }
#pragma unroll
        for (int off = 16; off > 0; off >>= 1) {
            d0 += __shfl_xor(d0, off, 64);
            d1 += __shfl_xor(d1, off, 64);
        }
        if (hl == 0) { dots[r0] = d0; dots[r0 + 1] = d1; }
        float s0v = sigmoidf(d0), s1v = sigmoidf(d1);
#pragma unroll
        for (int k = 0; k < 3; ++k) acc[k] += s0v * v0[k] + s1v * v1[k];
    }
#pragma unroll
    for (int k = 0; k < 3; ++k) {
        acc[k].x += __shfl_xor(acc[k].x, 32, 64);
        acc[k].y += __shfl_xor(acc[k].y, 32, 64);
        acc[k].z += __shfl_xor(acc[k].z, 32, 64);
        acc[k].w += __shfl_xor(acc[k].w, 32, 64);
    }
    if (half == 0) {
#pragma unroll
        for (int k = 0; k < 3; ++k) sacc[w][hl + 32 * k] = acc[k];
    }
    __syncthreads();

    // ---------- na reduce + per-batch sumsq(na), sumsq(cls) ----------
    float* escr = (float*)&eap[0][0];   // scratch (eap no longer needed)
    if (tid < C4) {
        f32x4 s = (f32x4)(0.f);
#pragma unroll
        for (int w2 = 0; w2 < 16; ++w2) s += sacc[w2][tid];
        ((f32x4*)(na + (size_t)b * C))[tid] = s;
        escr[tid] = dot4v(s, s);
        f32x4 cv = ((const f32x4*)(cls + (size_t)b * C))[tid];
        escr[C4 + tid] = dot4v(cv, cv);
    }
    __syncthreads();
    if (w == 0) {
        float nss = (lane < 32) ? (escr[lane] + escr[lane + 32] + escr[lane + 64]) : 0.f;
        float css = (lane < 32) ? (escr[C4 + lane] + escr[C4 + lane + 32] + escr[C4 + lane + 64]) : 0.f;
#pragma unroll
        for (int off = 32; off > 0; off >>= 1) {
            nss += __shfl_xor(nss, off, 64);
            css += __shfl_xor(css, off, 64);
        }
        if (lane == 0) { sqp[b] = nss; sqp[B + b] = css; }
    }

    // ---------- u64-key bitonic sort (stable ascending argsort) ----------
    float vv = dots[tid];
    unsigned u = __float_as_uint(vv);
    u = (u & 0x80000000u) ? ~u : (u | 0x80000000u);
    unsigned long long key = ((unsigned long long)u << 32) | (unsigned)tid;

    bool useA = true;
    for (int k = 2; k <= N; k <<= 1) {
        bool up = ((tid & k) == 0);
        for (int j = k >> 1; j > 0; j >>= 1) {
            unsigned long long other;
            if (j < 64) {
                other = __shfl_xor(key, j, 64);
            } else {
                unsigned long long* buf = useA ? bufA : bufB;
                useA = !useA;
                buf[tid] = key;
                __syncthreads();
                other = buf[tid ^ j];
            }
            bool iAmLow = ((tid & j) == 0);
            bool keepMin = (iAmLow == up);
            bool otherLess = (other < key);
            key = (keepMin == otherLess) ? other : key;
        }
    }
    __syncthreads();   // drain last LDS-stage reads

    // ---------- node-ascending (node, outpos) list ----------
    unsigned* flag = (unsigned*)bufA;
    flag[tid] = 0;
    __syncthreads();
    if (tid >= 768) flag[(unsigned)(key & 1023u)] = (unsigned)(tid - 768) | 0x80000000u;
    __syncthreads();
    unsigned f = flag[tid];
    bool sel = (f & 0x80000000u) != 0;
    unsigned long long bal = __ballot(sel);
    if (lane == 0) wsumS[w] = (unsigned)__popcll(bal);
    __syncthreads();
    if (sel) {
        int base = 0;
        for (int w2 = 0; w2 < w; ++w2) base += (int)wsumS[w2];
        int intra = (int)__popcll(bal & ((1ull << lane) - 1ull));
        llist[base + intra] = ((unsigned)tid << 8) | (f & 0xFFu);
    }
    __syncthreads();

    // ---------- gather 256 pooled rows (x rows L2/L3-warm from the x-pass) ----------
    const float* xb2 = x + ((size_t)b * XROWS + 1) * C;
#pragma unroll 8
    for (int q = 0; q < 24; ++q) {
        int e = tid + 1024 * q;
        int lp = e / C4, c4 = e % C4;
        unsigned ent = llist[lp];
        int node = (int)(ent >> 8);
        int op = (int)(ent & 0xFFu);
        f32x4 sv = *((const f32x4*)(xb2 + (size_t)node * C) + c4);
        __builtin_nontemporal_store(sv,
            (f32x4*)(out + ((size_t)b * OUTROWS + 1 + op) * C) + c4);
    }
}

// ---------------- kZ: finish global norms, write out[:,0,:] ----------------
__global__ __launch_bounds__(384) void kZ_cls(const float* __restrict__ sqp,
                                              const float* __restrict__ cls,
                                              const float* __restrict__ na,
                                              float* __restrict__ out) {
    int b = blockIdx.x, t = threadIdx.x;
    __shared__ float2 red[128];
    if (t < 128) red[t] = make_float2(sqp[t], sqp[B + t]);
    __syncthreads();
    for (int o = 64; o > 0; o >>= 1) {
        if (t < o) {
            float2 a = red[t], d = red[t + o];
            red[t] = make_float2(a.x + d.x, a.y + d.y);
        }
        __syncthreads();
    }
    float ratio = sqrtf(red[0].y / red[0].x);  // ||cls|| / ||na||
    out[((size_t)b * OUTROWS) * C + t] =
        cls[(size_t)b * C + t] + ratio * na[(size_t)b * C + t];
}

extern "C" void kernel_launch(void* const* d_in, const int* in_sizes, int n_in,
                              void* d_out, int out_size, void* d_ws, size_t ws_size,
                              hipStream_t stream) {
    const float* x   = (const float*)d_in[0];
    const float* cls = (const float*)d_in[1];
    const float* ea  = (const float*)d_in[2];
    float* out = (float*)d_out;
    float* ws  = (float*)d_ws;

    float* eaP = ws + OFF_EAP;
    float* na  = ws + OFF_NA;
    float* sqp = ws + OFF_SQ;

    k1_ea_partial<<<dim3(B, NS), 384, 0, stream>>>(ea, eaP);
    fatk<<<B, 1024, 0, stream>>>(x, cls, eaP, na, sqp, out);
    kZ_cls<<<B, 384, 0, stream>>>(sqp, cls, na, out);
}

// Round 5
// 90.420 us; speedup vs baseline: 1.4111x; 1.0160x over previous
//
#include <hip/hip_runtime.h>
#include <math.h>

#define B 128
#define N 1024
#define C 384
#define C4 96                   // C/4
#define NS 8                    // splits for ea partial pass
#define RPT (N / NS)            // 128
#define XROWS 1025
#define OUTROWS 257

typedef float f32x4 __attribute__((ext_vector_type(4)));

// workspace layout (float offsets)
#define OFF_EAP  0                       // [B][NS][C]
#define SZ_EAP   (B * NS * C)
#define OFF_NA   (OFF_EAP + SZ_EAP)      // [B][C]
#define SZ_NA    (B * C)
#define OFF_SQ   (OFF_NA + SZ_NA)        // [0,B): sumsq(na), [B,2B): sumsq(cls)
#define SZ_SQ    (2 * B)

__device__ __forceinline__ float sigmoidf(float v) { return 1.f / (1.f + expf(-v)); }
__device__ __forceinline__ float dot4v(f32x4 a, f32x4 b) {
    return a.x * b.x + a.y * b.y + a.z * b.z + a.w * b.w;
}

// ---------------- k1: partial column sums of edge_aggregation (f32x4, nontemporal) --------------
__global__ __launch_bounds__(384) void k1_ea_partial(const float* __restrict__ ea,
                                                     float* __restrict__ eaP) {
    int b = blockIdx.x, s = blockIdx.y, t = threadIdx.x;
    int rg = t / C4, c4 = t % C4;
    const f32x4* p = (const f32x4*)(ea + ((size_t)b * N + (size_t)s * RPT) * C);
    f32x4 acc = (f32x4)(0.f);
#pragma unroll 8
    for (int it = 0; it < RPT / 4; ++it)
        acc += __builtin_nontemporal_load(&p[(size_t)(it * 4 + rg) * C4 + c4]);
    __shared__ f32x4 lds[4][C4];
    lds[rg][c4] = acc;
    __syncthreads();
    if (t < C4) {
        f32x4 r = lds[0][t] + lds[1][t] + lds[2][t] + lds[3][t];
        ((f32x4*)(eaP + ((size_t)b * NS + s) * C))[t] = r;
    }
}

// ---------------- fatk: 1 block/batch: ci -> x-pass -> na/sumsq -> sort -> gather ----------------
__global__ __launch_bounds__(1024) void fatk(const float* __restrict__ x,
                                             const float* __restrict__ cls,
                                             const float* __restrict__ eaP,
                                             float* __restrict__ na,
                                             float* __restrict__ sqp,
                                             float* __restrict__ out) {
    int b = blockIdx.x, tid = threadIdx.x;
    int w = tid >> 6, lane = tid & 63, hl = lane & 31, half = lane >> 5;

    __shared__ f32x4 eap[NS][C4];           // 12 KB (later float scratch)
    __shared__ float sci[C];                // 1.5 KB
    __shared__ float dots[N];               // 4 KB
    __shared__ f32x4 sacc[16][C4];          // 24 KB
    __shared__ unsigned long long bufA[N];  // 8 KB
    __shared__ unsigned long long bufB[N];  // 8 KB
    __shared__ unsigned llist[256];         // 1 KB

    // ---------- ci = sigmoid(mean) from the NS eaP partials (12 KB, L2-hot) ----------
    if (tid < NS * C4) {
        int rg = tid / C4, c4 = tid % C4;
        eap[rg][c4] = ((const f32x4*)(eaP + ((size_t)b * NS + rg) * C))[c4];
    }
    __syncthreads();
    if (tid < C4) {
        f32x4 s = (f32x4)(0.f);
#pragma unroll
        for (int r = 0; r < NS; ++r) s += eap[r][tid];
        s *= (1.f / (float)N);
        sci[4 * tid + 0] = sigmoidf(s.x);
        sci[4 * tid + 1] = sigmoidf(s.y);
        sci[4 * tid + 2] = sigmoidf(s.z);
        sci[4 * tid + 3] = sigmoidf(s.w);
    }
    __syncthreads();

    // ---------- x-pass: per-row dot + sigmoid-weighted accumulate (all 1024 rows) ----------
    f32x4 cir[3];
#pragma unroll
    for (int k = 0; k < 3; ++k) cir[k] = ((const f32x4*)sci)[hl + 32 * k];
    f32x4 acc[3];
#pragma unroll
    for (int k = 0; k < 3; ++k) acc[k] = (f32x4)(0.f);

    const float* xb = x + (size_t)b * XROWS * C + C;   // nodes base (skip cls row)
#pragma unroll 2
    for (int it = 0; it < 32; ++it) {
        int r = 32 * it + 2 * w + half;
        const f32x4* rp = (const f32x4*)(xb + (size_t)r * C);
        f32x4 v[3];
        float dotv = 0.f;
#pragma unroll
        for (int k = 0; k < 3; ++k) {
            v[k] = rp[hl + 32 * k];
            dotv += dot4v(v[k], cir[k]);
        }
#pragma unroll
        for (int off = 16; off > 0; off >>= 1) dotv += __shfl_xor(dotv, off, 64);
        if (hl == 0) dots[r] = dotv;
        float si = sigmoidf(dotv);
#pragma unroll
        for (int k = 0; k < 3; ++k) acc[k] += si * v[k];
    }
#pragma unroll
    for (int k = 0; k < 3; ++k) {
        acc[k].x += __shfl_xor(acc[k].x, 32, 64);
        acc[k].y += __shfl_xor(acc[k].y, 32, 64);
        acc[k].z += __shfl_xor(acc[k].z, 32, 64);
        acc[k].w += __shfl_xor(acc[k].w, 32, 64);
    }
    if (half == 0) {
#pragma unroll
        for (int k = 0; k < 3; ++k) sacc[w][hl + 32 * k] = acc[k];
    }
    __syncthreads();

    // ---------- na reduce + per-batch sumsq(na), sumsq(cls) ----------
    float* escr = (float*)&eap[0][0];   // scratch (eap no longer needed)
    if (tid < C4) {
        f32x4 s = (f32x4)(0.f);
#pragma unroll
        for (int w2 = 0; w2 < 16; ++w2) s += sacc[w2][tid];
        ((f32x4*)(na + (size_t)b * C))[tid] = s;
        escr[tid] = dot4v(s, s);
        f32x4 cv = ((const f32x4*)(cls + (size_t)b * C))[tid];
        escr[C4 + tid] = dot4v(cv, cv);
    }
    __syncthreads();
    if (w == 0) {
        float nss = (lane < 32) ? (escr[lane] + escr[lane + 32] + escr[lane + 64]) : 0.f;
        float css = (lane < 32) ? (escr[C4 + lane] + escr[C4 + lane + 32] + escr[C4 + lane + 64]) : 0.f;
#pragma unroll
        for (int off = 32; off > 0; off >>= 1) {
            nss += __shfl_xor(nss, off, 64);
            css += __shfl_xor(css, off, 64);
        }
        if (lane == 0) { sqp[b] = nss; sqp[B + b] = css; }
    }

    // ---------- u64-key bitonic sort (stable ascending argsort) ----------
    float vv = dots[tid];
    unsigned u = __float_as_uint(vv);
    u = (u & 0x80000000u) ? ~u : (u | 0x80000000u);
    unsigned long long key = ((unsigned long long)u << 32) | (unsigned)tid;

    bool useA = true;
    for (int k = 2; k <= N; k <<= 1) {
        bool up = ((tid & k) == 0);
        for (int j = k >> 1; j > 0; j >>= 1) {
            unsigned long long other;
            if (j < 64) {
                other = __shfl_xor(key, j, 64);
            } else {
                unsigned long long* buf = useA ? bufA : bufB;
                useA = !useA;
                buf[tid] = key;
                __syncthreads();
                other = buf[tid ^ j];
            }
            bool iAmLow = ((tid & j) == 0);
            bool keepMin = (iAmLow == up);
            bool otherLess = (other < key);
            key = (keepMin == otherLess) ? other : key;
        }
    }
    __syncthreads();   // drain last LDS-stage reads

    // ---------- node-ascending (node, outpos) list ----------
    unsigned* flag = (unsigned*)bufA;
    unsigned* wsum = (unsigned*)bufB;
    flag[tid] = 0;
    __syncthreads();
    if (tid >= 768) flag[(unsigned)(key & 1023u)] = (unsigned)(tid - 768) | 0x80000000u;
    __syncthreads();
    unsigned f = flag[tid];
    bool sel = (f & 0x80000000u) != 0;
    unsigned long long bal = __ballot(sel);
    if (lane == 0) wsum[w] = (unsigned)__popcll(bal);
    __syncthreads();
    if (sel) {
        int base = 0;
        for (int w2 = 0; w2 < w; ++w2) base += (int)wsum[w2];
        int intra = (int)__popcll(bal & ((1ull << lane) - 1ull));
        llist[base + intra] = ((unsigned)tid << 8) | (f & 0xFFu);
    }
    __syncthreads();

    // ---------- gather 256 pooled rows (x rows L2/L3-warm from the x-pass) ----------
    const float* xb2 = x + ((size_t)b * XROWS + 1) * C;
#pragma unroll 4
    for (int q = 0; q < 24; ++q) {
        int e = tid + 1024 * q;
        int lp = e / C4, c4 = e % C4;
        unsigned ent = llist[lp];
        int node = (int)(ent >> 8);
        int op = (int)(ent & 0xFFu);
        f32x4 sv = *((const f32x4*)(xb2 + (size_t)node * C) + c4);
        __builtin_nontemporal_store(sv,
            (f32x4*)(out + ((size_t)b * OUTROWS + 1 + op) * C) + c4);
    }
}

// ---------------- kZ: finish global norms, write out[:,0,:] ----------------
__global__ __launch_bounds__(384) void kZ_cls(const float* __restrict__ sqp,
                                              const float* __restrict__ cls,
                                              const float* __restrict__ na,
                                              float* __restrict__ out) {
    int b = blockIdx.x, t = threadIdx.x;
    __shared__ float2 red[128];
    if (t < 128) red[t] = make_float2(sqp[t], sqp[B + t]);
    __syncthreads();
    for (int o = 64; o > 0; o >>= 1) {
        if (t < o) {
            float2 a = red[t], d = red[t + o];
            red[t] = make_float2(a.x + d.x, a.y + d.y);
        }
        __syncthreads();
    }
    float ratio = sqrtf(red[0].y / red[0].x);  // ||cls|| / ||na||
    out[((size_t)b * OUTROWS) * C + t] =
        cls[(size_t)b * C + t] + ratio * na[(size_t)b * C + t];
}

extern "C" void kernel_launch(void* const* d_in, const int* in_sizes, int n_in,
                              void* d_out, int out_size, void* d_ws, size_t ws_size,
                              hipStream_t stream) {
    const float* x   = (const float*)d_in[0];
    const float* cls = (const float*)d_in[1];
    const float* ea  = (const float*)d_in[2];
    float* out = (float*)d_out;
    float* ws  = (float*)d_ws;

    float* eaP = ws + OFF_EAP;
    float* na  = ws + OFF_NA;
    float* sqp = ws + OFF_SQ;

    k1_ea_partial<<<dim3(B, NS), 384, 0, stream>>>(ea, eaP);
    fatk<<<B, 1024, 0, stream>>>(x, cls, eaP, na, sqp, out);
    kZ_cls<<<B, 384, 0, stream>>>(sqp, cls, na, out);
}